// Round 5
// baseline (921.687 us; speedup 1.0000x reference)
//
#include <hip/hip_runtime.h>
#include <math.h>

#define NT_NODES 30000
#define NE_EDGES 200000
#define NTY 3
#define NRL 4
#define NLY 2
#define NH 8
#define HD 16
#define FDIM 128
#define SCAN_BLOCKS 118   // ceil(30000/256)

typedef unsigned short u16;
typedef unsigned int u32;

__device__ __forceinline__ float bf2f(u16 u) {
  return __uint_as_float(((u32)u) << 16);
}
__device__ __forceinline__ u16 f2bf(float f) {   // RNE
  u32 u = __float_as_uint(f);
  return (u16)((u + 0x7FFFu + ((u >> 16) & 1u)) >> 16);
}

// ---------------------------------------------------------------- GEMM ------
struct GemmTask {
  const float* A; const float* W; const float* bias; float* C;
  const float* oldh; const float* skipp;
};
struct GemmBatch { GemmTask t[7]; };

__device__ __forceinline__ float gelu_f(float x) {
  return 0.5f * x * (1.f + erff(x * 0.7071067811865475f));
}

// C[M,128] = epi(preA(A)[M,128] @ W[128,128] + bias)
template<int GELU_A, int EPI_SKIP, int RELU, int BF16_OUT>
__global__ __launch_bounds__(256) void gemm_f32(GemmBatch gb, int M) {
  const GemmTask tk = gb.t[blockIdx.z];
  const int tid = threadIdx.x;
  const int tx2 = tid & 15;    // col group of 8
  const int ty2 = tid >> 4;    // row group of 4
  const int row0 = blockIdx.x * 64;

  __shared__ float AsT[32][64];   // transposed A chunk [k][row]
  __shared__ float Bs[32][128];   // B chunk [k][col]

  float acc[4][8];
  #pragma unroll
  for (int i = 0; i < 4; i++)
    #pragma unroll
    for (int j = 0; j < 8; j++) acc[i][j] = 0.f;

  for (int k0 = 0; k0 < FDIM; k0 += 32) {
    #pragma unroll
    for (int i = 0; i < 2; i++) {
      int slot = tid + 256 * i;         // 0..511
      int r = slot >> 3, f4 = slot & 7;
      int grow = row0 + r;
      float4 v = make_float4(0.f, 0.f, 0.f, 0.f);
      if (grow < M) v = *(const float4*)(tk.A + (size_t)grow * FDIM + k0 + f4 * 4);
      if (GELU_A) { v.x = gelu_f(v.x); v.y = gelu_f(v.y); v.z = gelu_f(v.z); v.w = gelu_f(v.w); }
      AsT[f4 * 4 + 0][r] = v.x;
      AsT[f4 * 4 + 1][r] = v.y;
      AsT[f4 * 4 + 2][r] = v.z;
      AsT[f4 * 4 + 3][r] = v.w;
    }
    #pragma unroll
    for (int i = 0; i < 4; i++) {
      int slot = tid + 256 * i;         // 0..1023
      int r = slot >> 5, f4 = slot & 31;
      float4 v = *(const float4*)(tk.W + (size_t)(k0 + r) * FDIM + f4 * 4);
      *(float4*)(&Bs[r][f4 * 4]) = v;
    }
    __syncthreads();
    #pragma unroll
    for (int kk = 0; kk < 32; kk++) {
      float4 a4 = *(const float4*)(&AsT[kk][ty2 * 4]);
      float4 b0 = *(const float4*)(&Bs[kk][tx2 * 8]);
      float4 b1 = *(const float4*)(&Bs[kk][tx2 * 8 + 4]);
      const float av[4] = {a4.x, a4.y, a4.z, a4.w};
      #pragma unroll
      for (int i = 0; i < 4; i++) {
        acc[i][0] += av[i] * b0.x; acc[i][1] += av[i] * b0.y;
        acc[i][2] += av[i] * b0.z; acc[i][3] += av[i] * b0.w;
        acc[i][4] += av[i] * b1.x; acc[i][5] += av[i] * b1.y;
        acc[i][6] += av[i] * b1.z; acc[i][7] += av[i] * b1.w;
      }
    }
    __syncthreads();
  }

  float4 bias0 = *(const float4*)(tk.bias + tx2 * 8);
  float4 bias1 = *(const float4*)(tk.bias + tx2 * 8 + 4);
  float a_s = 0.f;
  if (EPI_SKIP) a_s = 1.f / (1.f + expf(-tk.skipp[0]));

  #pragma unroll
  for (int i = 0; i < 4; i++) {
    int grow = row0 + ty2 * 4 + i;
    if (grow >= M) continue;
    float o[8];
    o[0] = acc[i][0] + bias0.x; o[1] = acc[i][1] + bias0.y;
    o[2] = acc[i][2] + bias0.z; o[3] = acc[i][3] + bias0.w;
    o[4] = acc[i][4] + bias1.x; o[5] = acc[i][5] + bias1.y;
    o[6] = acc[i][6] + bias1.z; o[7] = acc[i][7] + bias1.w;
    if (RELU) {
      #pragma unroll
      for (int j = 0; j < 8; j++) o[j] = fmaxf(o[j], 0.f);
    }
    if (EPI_SKIP) {
      const float* hp = tk.oldh + (size_t)grow * FDIM + tx2 * 8;
      float4 h0 = *(const float4*)(hp);
      float4 h1 = *(const float4*)(hp + 4);
      float b_s = 1.f - a_s;
      o[0] = a_s * o[0] + b_s * h0.x; o[1] = a_s * o[1] + b_s * h0.y;
      o[2] = a_s * o[2] + b_s * h0.z; o[3] = a_s * o[3] + b_s * h0.w;
      o[4] = a_s * o[4] + b_s * h1.x; o[5] = a_s * o[5] + b_s * h1.y;
      o[6] = a_s * o[6] + b_s * h1.z; o[7] = a_s * o[7] + b_s * h1.w;
    }
    if (BF16_OUT) {
      u32 p0 = (u32)f2bf(o[0]) | ((u32)f2bf(o[1]) << 16);
      u32 p1 = (u32)f2bf(o[2]) | ((u32)f2bf(o[3]) << 16);
      u32 p2 = (u32)f2bf(o[4]) | ((u32)f2bf(o[5]) << 16);
      u32 p3 = (u32)f2bf(o[6]) | ((u32)f2bf(o[7]) << 16);
      u16* cp = ((u16*)tk.C) + (size_t)grow * FDIM + tx2 * 8;
      *(uint4*)cp = make_uint4(p0, p1, p2, p3);
    } else {
      float* cp = tk.C + (size_t)grow * FDIM + tx2 * 8;
      *(float4*)cp = make_float4(o[0], o[1], o[2], o[3]);
      *(float4*)(cp + 4) = make_float4(o[4], o[5], o[6], o[7]);
    }
  }
}

// ------------------------------------------------------------- CSR build ----
__global__ __launch_bounds__(256) void csr_hist(const int* __restrict__ edge_index,
                                                int* __restrict__ counts) {
  int idx = blockIdx.x * 256 + threadIdx.x;
  if (idx >= NRL * NE_EDGES) return;
  int r = idx / NE_EDGES, e = idx - r * NE_EDGES;
  int d = edge_index[(size_t)(r * 2 + 1) * NE_EDGES + e];
  atomicAdd(&counts[r * NT_NODES + d], 1);
}

// hierarchical scan: block-local -> aux -> add-back
__global__ __launch_bounds__(256) void scan_block(const int* __restrict__ counts,
                                                  int* __restrict__ off,
                                                  int* __restrict__ aux) {
  int r = blockIdx.y, b = blockIdx.x, t = threadIdx.x;
  int i = b * 256 + t;
  int v = (i < NT_NODES) ? counts[r * NT_NODES + i] : 0;
  __shared__ int lds[256];
  lds[t] = v;
  __syncthreads();
  #pragma unroll
  for (int dlt = 1; dlt < 256; dlt <<= 1) {
    int x = (t >= dlt) ? lds[t - dlt] : 0;
    __syncthreads();
    lds[t] += x;
    __syncthreads();
  }
  if (i < NT_NODES) off[(size_t)r * (NT_NODES + 1) + i] = lds[t] - v;  // block-local exclusive
  if (t == 255) aux[r * SCAN_BLOCKS + b] = lds[255];
}

__global__ __launch_bounds__(128) void scan_aux(const int* __restrict__ aux,
                                                int* __restrict__ auxe,
                                                int* __restrict__ off) {
  int r = blockIdx.x, t = threadIdx.x;
  __shared__ int lds[128];
  int v = (t < SCAN_BLOCKS) ? aux[r * SCAN_BLOCKS + t] : 0;
  lds[t] = v;
  __syncthreads();
  #pragma unroll
  for (int dlt = 1; dlt < 128; dlt <<= 1) {
    int x = (t >= dlt) ? lds[t - dlt] : 0;
    __syncthreads();
    lds[t] += x;
    __syncthreads();
  }
  if (t < SCAN_BLOCKS) auxe[r * SCAN_BLOCKS + t] = lds[t] - v;   // exclusive
  if (t == 127) off[(size_t)r * (NT_NODES + 1) + NT_NODES] = lds[127];  // grand total
}

__global__ __launch_bounds__(256) void scan_add(const int* __restrict__ auxe,
                                                int* __restrict__ off,
                                                int* __restrict__ cursor) {
  int r = blockIdx.y, b = blockIdx.x, t = threadIdx.x;
  int i = b * 256 + t;
  if (i >= NT_NODES) return;
  int val = off[(size_t)r * (NT_NODES + 1) + i] + auxe[r * SCAN_BLOCKS + b];
  off[(size_t)r * (NT_NODES + 1) + i] = val;
  cursor[r * NT_NODES + i] = val;
}

__global__ __launch_bounds__(256) void csr_scatter(const int* __restrict__ edge_index,
                                                   int* __restrict__ cursor,
                                                   int* __restrict__ csr_src) {
  int idx = blockIdx.x * 256 + threadIdx.x;
  if (idx >= NRL * NE_EDGES) return;
  int r = idx / NE_EDGES, e = idx - r * NE_EDGES;
  int s = edge_index[(size_t)(r * 2 + 0) * NE_EDGES + e];
  int d = edge_index[(size_t)(r * 2 + 1) * NE_EDGES + e];
  int pos = atomicAdd(&cursor[r * NT_NODES + d], 1);
  csr_src[(size_t)r * NE_EDGES + pos] = s;
}

// ---------------------------------------------------- fused attention -------
// One wave per dst node per relation. Lane owns channel PAIR {2l, 2l+1} (bf16).
// Head h = lane>>3 (8 lanes per head). q' = (A_rel q)*p/4 via shfl; online
// accumulation of (sum e*v_raw, sum e); epilogue applies M_rel per head.
// accum=0: overwrite agg row; accum=1: add (relation sharing a dst type).
struct AttnRel {
  const int* csr_src; const int* off;
  const u16* q;        // bf16 Q of dst type [N,128]
  const u16* kraw;     // bf16 raw K of src type [N,128]
  const u16* vraw;     // bf16 raw V of src type [N,128]
  const float* Arel;   // [8][16][16]
  const float* Mrel;   // [8][16][16]
  const float* prel;   // [8]
  float* agg;          // agg of dst type [N,128]
  int accum;
};
struct AttnBatch { AttnRel r[3]; };

__global__ __launch_bounds__(256) void attn_fused(AttnBatch ab) {
  const AttnRel rp = ab.r[blockIdx.y];
  const int wave = threadIdx.x >> 6;
  const int lane = threadIdx.x & 63;
  const int d = blockIdx.x * 4 + wave;
  if (d >= NT_NODES) return;
  const int h = lane >> 3;         // head 0..7
  const int el = lane & 7;         // pair index within head (channels 2el,2el+1)
  const int grp = h << 3;          // first lane of this head's group

  // ---- q' = (A_h @ q_h) * p_h/4 via shfl within 8-lane head groups ----
  ushort2 qu = ((const ushort2*)rp.q)[(size_t)d * 64 + lane];
  float q0 = bf2f(qu.x), q1 = bf2f(qu.y);
  const float* A = rp.Arel + (size_t)h * 256;
  float qp0 = 0.f, qp1 = 0.f;
  #pragma unroll
  for (int ee = 0; ee < 8; ee++) {
    float qa = __shfl(q0, grp + ee, 64);     // q_e, e=2ee
    float qb = __shfl(q1, grp + ee, 64);     // q_e, e=2ee+1
    qp0 += A[(2 * el) * 16 + 2 * ee] * qa + A[(2 * el) * 16 + 2 * ee + 1] * qb;
    qp1 += A[(2 * el + 1) * 16 + 2 * ee] * qa + A[(2 * el + 1) * 16 + 2 * ee + 1] * qb;
  }
  float sc = rp.prel[h] * 0.25f;
  qp0 *= sc; qp1 *= sc;

  // ---- edge loop: gather bf16 K/V rows, online accumulate ----
  int lo = rp.off[d], hi = rp.off[d + 1];
  float acc0 = 0.f, acc1 = 0.f, ssum = 0.f;
  #pragma unroll 2
  for (int pos = lo; pos < hi; pos++) {
    int s = rp.csr_src[pos];
    ushort2 ku = ((const ushort2*)rp.kraw)[(size_t)s * 64 + lane];
    ushort2 vu = ((const ushort2*)rp.vraw)[(size_t)s * 64 + lane];
    float pd = qp0 * bf2f(ku.x) + qp1 * bf2f(ku.y);
    pd += __shfl_xor(pd, 1, 64);
    pd += __shfl_xor(pd, 2, 64);
    pd += __shfl_xor(pd, 4, 64);
    float ev = __expf(pd);
    acc0 += ev * bf2f(vu.x);
    acc1 += ev * bf2f(vu.y);
    ssum += ev;
  }
  float inv = 1.f / (ssum + 1e-16f);
  float S0 = acc0 * inv, S1 = acc1 * inv;   // raw-V aggregate, d2 = 2el, 2el+1

  // ---- apply M_rel: out_j = sum_d2 S[d2] * M[h][d2][j], j = 2el, 2el+1 ----
  const float* M = rp.Mrel + (size_t)h * 256;
  float o0 = 0.f, o1 = 0.f;
  #pragma unroll
  for (int dd = 0; dd < 8; dd++) {
    float sa = __shfl(S0, grp + dd, 64);     // S_{2dd}
    float sb = __shfl(S1, grp + dd, 64);     // S_{2dd+1}
    o0 += sa * M[(2 * dd) * 16 + 2 * el] + sb * M[(2 * dd + 1) * 16 + 2 * el];
    o1 += sa * M[(2 * dd) * 16 + 2 * el + 1] + sb * M[(2 * dd + 1) * 16 + 2 * el + 1];
  }
  float* ap = rp.agg + (size_t)d * FDIM + 2 * lane;
  if (rp.accum) {
    float2 old = *(float2*)ap;
    *(float2*)ap = make_float2(old.x + o0, old.y + o1);
  } else {
    *(float2*)ap = make_float2(o0, o1);
  }
}

// ---------------------------------------------------------------- scatter ---
__global__ __launch_bounds__(256) void scatter_out(const float* h0, const float* h1,
                                                   const float* h2, const int* ntype,
                                                   float* out, int NN) {
  int idx = blockIdx.x * 256 + threadIdx.x;
  if (idx >= NN * 32) return;
  int i = idx >> 5, c4 = idx & 31;
  int t = ntype[i];
  const float* hp = (t == 0) ? h0 : ((t == 1) ? h1 : h2);
  int local = i - t * NT_NODES;   // node_type_argmax is contiguous blocks per type
  ((float4*)out)[idx] = ((const float4*)hp)[(size_t)local * 32 + c4];
}

// ------------------------------------------------------------------- host ---
static const int ESRC[NRL] = {0, 0, 1, 0};
static const int EDST[NRL] = {0, 1, 0, 2};

extern "C" void kernel_launch(void* const* d_in, const int* in_sizes, int n_in,
                              void* d_out, int out_size, void* d_ws, size_t ws_size,
                              hipStream_t stream) {
  const float* x[3] = {(const float*)d_in[0], (const float*)d_in[1], (const float*)d_in[2]};
  const float* lin_w = (const float*)d_in[4];
  const float* lin_b = (const float*)d_in[5];
  const float* k_w   = (const float*)d_in[6];
  const float* k_b   = (const float*)d_in[7];
  const float* q_w   = (const float*)d_in[8];
  const float* q_b   = (const float*)d_in[9];
  const float* v_w   = (const float*)d_in[10];
  const float* v_b   = (const float*)d_in[11];
  const float* a_w   = (const float*)d_in[12];
  const float* a_b   = (const float*)d_in[13];
  const float* skip  = (const float*)d_in[14];
  const float* a_rel = (const float*)d_in[15];
  const float* m_rel = (const float*)d_in[16];
  const float* p_rel = (const float*)d_in[17];
  const int* edge_index = (const int*)d_in[18];
  const int* ntype   = (const int*)d_in[19];
  float* out = (float*)d_out;

  const size_t NF = (size_t)NT_NODES * FDIM;   // 3.84M elems per [N,128]
  float* p = (float*)d_ws;
  auto alloc = [&](size_t n) { float* r = p; p += n; return r; };
  float* bufA = alloc(3 * NF);                    // h (ping)
  float* bufB = alloc(3 * NF);                    // h (pong); bf16 Q aliases alt
  float* agg  = alloc(3 * NF);                    // edge aggregation (raw-V space)
  u16* kbf0 = (u16*)alloc(NF / 2);                // bf16 K, src type 0
  u16* vbf0 = (u16*)alloc(NF / 2);                // bf16 V, src type 0
  u16* kbf1 = (u16*)alloc(NF / 2);                // bf16 K, src type 1
  u16* vbf1 = (u16*)alloc(NF / 2);                // bf16 V, src type 1
  int* counts  = (int*)(p);                       // [4][N]
  int* cursor  = counts + NRL * NT_NODES;         // [4][N]
  int* offsets = cursor + NRL * NT_NODES;         // [4][N+1]
  int* aux     = offsets + NRL * (NT_NODES + 1);  // [4][118]
  int* auxe    = aux + NRL * SCAN_BLOCKS;         // [4][118]
  int* csr_src = auxe + NRL * SCAN_BLOCKS;        // [4][E]

  const int gemm_gx = (NT_NODES + 63) / 64;   // 469

  // ---- CSR build (edge_index fixed within a call; reused by both layers) ----
  hipMemsetAsync(counts, 0, NRL * NT_NODES * sizeof(int), stream);
  csr_hist<<<dim3((NRL * NE_EDGES + 255) / 256), 256, 0, stream>>>(edge_index, counts);
  scan_block<<<dim3(SCAN_BLOCKS, NRL), 256, 0, stream>>>(counts, offsets, aux);
  scan_aux<<<dim3(NRL), 128, 0, stream>>>(aux, auxe, offsets);
  scan_add<<<dim3(SCAN_BLOCKS, NRL), 256, 0, stream>>>(auxe, offsets, cursor);
  csr_scatter<<<dim3((NRL * NE_EDGES + 255) / 256), 256, 0, stream>>>(edge_index, cursor, csr_src);

  // input projection: hs[t] = relu(x_t @ lin_w[t] + lin_b[t])
  {
    GemmBatch gb{};
    for (int t = 0; t < 3; t++) {
      gb.t[t].A = x[t];
      gb.t[t].W = lin_w + (size_t)t * FDIM * FDIM;
      gb.t[t].bias = lin_b + (size_t)t * FDIM;
      gb.t[t].C = bufA + (size_t)t * NF;
    }
    gemm_f32<0, 0, 1, 0><<<dim3(gemm_gx, 1, 3), 256, 0, stream>>>(gb, NT_NODES);
  }

  float* cur = bufA;   // current h (fp32)
  float* alt = bufB;   // bf16 Q scratch now, fp32 next-h later
  for (int l = 0; l < NLY; l++) {
    u16* qbf = (u16*)alt;

    // Q for all 3 types + raw K/V for src types 0 and 1 — all bf16, one launch
    {
      GemmBatch gb{};
      for (int t = 0; t < 3; t++) {
        gb.t[t].A = cur + (size_t)t * NF;
        gb.t[t].W = q_w + (size_t)(l * NTY + t) * FDIM * FDIM;
        gb.t[t].bias = q_b + (size_t)(l * NTY + t) * FDIM;
        gb.t[t].C = (float*)(qbf + (size_t)t * NF);
      }
      gb.t[3].A = cur;                                   // src type 0
      gb.t[3].W = k_w + (size_t)(l * NTY + 0) * FDIM * FDIM;
      gb.t[3].bias = k_b + (size_t)(l * NTY + 0) * FDIM;
      gb.t[3].C = (float*)kbf0;
      gb.t[4].A = cur;
      gb.t[4].W = v_w + (size_t)(l * NTY + 0) * FDIM * FDIM;
      gb.t[4].bias = v_b + (size_t)(l * NTY + 0) * FDIM;
      gb.t[4].C = (float*)vbf0;
      gb.t[5].A = cur + NF;                              // src type 1
      gb.t[5].W = k_w + (size_t)(l * NTY + 1) * FDIM * FDIM;
      gb.t[5].bias = k_b + (size_t)(l * NTY + 1) * FDIM;
      gb.t[5].C = (float*)kbf1;
      gb.t[6].A = cur + NF;
      gb.t[6].W = v_w + (size_t)(l * NTY + 1) * FDIM * FDIM;
      gb.t[6].bias = v_b + (size_t)(l * NTY + 1) * FDIM;
      gb.t[6].C = (float*)vbf1;
      gemm_f32<0, 0, 0, 1><<<dim3(gemm_gx, 1, 7), 256, 0, stream>>>(gb, NT_NODES);
    }

    // attention launch A: relations {0,1,3} (src type 0; dst types 0,1,2
    // disjoint -> agg overwritten, no memset needed)
    {
      AttnBatch ab{};
      const int rels[3] = {0, 1, 3};
      for (int j = 0; j < 3; j++) {
        int r = rels[j], dt = EDST[r];
        ab.r[j].csr_src = csr_src + (size_t)r * NE_EDGES;
        ab.r[j].off  = offsets + (size_t)r * (NT_NODES + 1);
        ab.r[j].q    = qbf + (size_t)dt * NF;
        ab.r[j].kraw = kbf0;
        ab.r[j].vraw = vbf0;
        ab.r[j].Arel = a_rel + (size_t)(l * NRL + r) * NH * HD * HD;
        ab.r[j].Mrel = m_rel + (size_t)(l * NRL + r) * NH * HD * HD;
        ab.r[j].prel = p_rel + (size_t)(l * NRL + r) * NH;
        ab.r[j].agg  = agg + (size_t)dt * NF;
        ab.r[j].accum = 0;
      }
      attn_fused<<<dim3((NT_NODES + 3) / 4, 3), 256, 0, stream>>>(ab);
    }

    // attention launch B: relation {2} (src type 1, dst type 0, accumulate)
    {
      AttnBatch ab{};
      int r = 2, dt = EDST[r];
      ab.r[0].csr_src = csr_src + (size_t)r * NE_EDGES;
      ab.r[0].off  = offsets + (size_t)r * (NT_NODES + 1);
      ab.r[0].q    = qbf + (size_t)dt * NF;
      ab.r[0].kraw = kbf1;
      ab.r[0].vraw = vbf1;
      ab.r[0].Arel = a_rel + (size_t)(l * NRL + r) * NH * HD * HD;
      ab.r[0].Mrel = m_rel + (size_t)(l * NRL + r) * NH * HD * HD;
      ab.r[0].prel = p_rel + (size_t)(l * NRL + r) * NH;
      ab.r[0].agg  = agg + (size_t)dt * NF;
      ab.r[0].accum = 1;
      attn_fused<<<dim3((NT_NODES + 3) / 4, 1), 256, 0, stream>>>(ab);
    }

    // out: hs_new[t] = a_s*(gelu(agg[t]) @ a_w + a_b) + (1-a_s)*hs[t]
    // writes fp32 over the (dead) bf16 q scratch
    {
      GemmBatch gb{};
      for (int t = 0; t < 3; t++) {
        gb.t[t].A = agg + (size_t)t * NF;
        gb.t[t].W = a_w + (size_t)(l * NTY + t) * FDIM * FDIM;
        gb.t[t].bias = a_b + (size_t)(l * NTY + t) * FDIM;
        gb.t[t].C = alt + (size_t)t * NF;
        gb.t[t].oldh = cur + (size_t)t * NF;
        gb.t[t].skipp = skip + (size_t)(l * NTY + t);
      }
      gemm_f32<1, 1, 0, 0><<<dim3(gemm_gx, 1, 3), 256, 0, stream>>>(gb, NT_NODES);
    }
    float* tmp = cur; cur = alt; alt = tmp;
  }

  // scatter per-type rows back to global node order
  const int NN = 3 * NT_NODES;
  scatter_out<<<dim3((NN * 32 + 255) / 256), 256, 0, stream>>>(
      cur, cur + NF, cur + 2 * NF, ntype, out, NN);
}